// Round 2
// baseline (1181.274 us; speedup 1.0000x reference)
//
#include <hip/hip_runtime.h>
#include <hip/hip_bf16.h>

// TGAT fused forward on MI355X (gfx950).
// Shapes: B=4096, N=64, D=De=Dt=128, M=384, H=2, DK=192.
// R1 redesign: mega keeps KV in MFMA accumulator fragments (no 97KB LDS
// round-trip): scores via per-lane partial dot + lr-butterfly, PV via
// lg-butterfly. LDS 117KB->53KB => 2 blocks/CU. All weights repacked
// fragment-major (1KB contiguous wave loads). qproj/tail: 16-row tiles,
// 256 blocks (was 64-block quarter-chip latency traps).

typedef __attribute__((ext_vector_type(8))) short bf16x8_t;   // 8 bf16 in 4 VGPRs
typedef __attribute__((ext_vector_type(4))) float f32x4_t;    // MFMA accumulator

__device__ __forceinline__ float bf2f(unsigned short s) {
  union { unsigned u; float f; } v; v.u = ((unsigned)s) << 16; return v.f;
}
__device__ __forceinline__ unsigned short f2bf(float f) {
  union { float f; unsigned u; } v; v.f = f;
  return (unsigned short)((v.u + 0x7fffu + ((v.u >> 16) & 1u)) >> 16);  // RNE
}
__device__ __forceinline__ bf16x8_t pack8(float4 a, float4 b) {
  bf16x8_t t;
  t[0] = (short)f2bf(a.x); t[1] = (short)f2bf(a.y);
  t[2] = (short)f2bf(a.z); t[3] = (short)f2bf(a.w);
  t[4] = (short)f2bf(b.x); t[5] = (short)f2bf(b.y);
  t[6] = (short)f2bf(b.z); t[7] = (short)f2bf(b.w);
  return t;
}

// ---------------------------------------------------------------------------
// Kernel 1: repack all weights to bf16 FRAGMENT-MAJOR layouts.
// For W[C][K]: packed[(c16*(K/32)+kk)*512 + l*8 + j] = W[c16*16+(l&15)][kk*32+(l>>4)*8+j]
// so a wave's MFMA B-fragment load is one contiguous 1KB burst.
// Segments (in 8-elem fragments): wq2 12288 | wkv2 36864 | wo2 18432 | w12 8192 | w22 2048
// ---------------------------------------------------------------------------
__global__ __launch_bounds__(256) void prep_kernel(
    const float* __restrict__ Wq, const float* __restrict__ Wk,
    const float* __restrict__ Wv, const float* __restrict__ Wo,
    const float* __restrict__ W1, const float* __restrict__ W2,
    unsigned short* __restrict__ wq2, unsigned short* __restrict__ wkv2,
    unsigned short* __restrict__ wo2, unsigned short* __restrict__ w12,
    unsigned short* __restrict__ w22) {
  int f = blockIdx.x * 256 + threadIdx.x;
  if (f >= 77824) return;
  const float* sp;
  unsigned short* dp;
  if (f < 12288) {                    // wq2: C=384, Keff=256 (skip Wq cols 128..255)
    int lf = f, l = lf & 63, rest = lf >> 6;
    int kk = rest & 7, c16 = rest >> 3;
    int r = c16 * 16 + (l & 15), k0 = kk * 32 + (l >> 4) * 8;
    int m0 = (k0 < 128) ? k0 : k0 + 128;
    sp = Wq + (size_t)r * 384 + m0;
    dp = wq2 + (size_t)lf * 8;
  } else if (f < 12288 + 36864) {     // wkv2: C=768 (Wk rows then Wv rows), K=384
    int lf = f - 12288, l = lf & 63, rest = lf >> 6;
    int kk = rest % 12, c16 = rest / 12;
    int j = c16 * 16 + (l & 15), m0 = kk * 32 + (l >> 4) * 8;
    sp = (j < 384 ? Wk + (size_t)j * 384 : Wv + (size_t)(j - 384) * 384) + m0;
    dp = wkv2 + (size_t)lf * 8;
  } else if (f < 12288 + 36864 + 18432) {  // wo2: C=384, K=384
    int lf = f - (12288 + 36864), l = lf & 63, rest = lf >> 6;
    int kk = rest % 12, c16 = rest / 12;
    sp = Wo + (size_t)(c16 * 16 + (l & 15)) * 384 + kk * 32 + (l >> 4) * 8;
    dp = wo2 + (size_t)lf * 8;
  } else if (f < 12288 + 36864 + 18432 + 8192) {  // w12: C=128, K=512
    int lf = f - (12288 + 36864 + 18432), l = lf & 63, rest = lf >> 6;
    int kk = rest & 15, c16 = rest >> 4;
    sp = W1 + (size_t)(c16 * 16 + (l & 15)) * 512 + kk * 32 + (l >> 4) * 8;
    dp = w12 + (size_t)lf * 8;
  } else {                            // w22: C=128, K=128
    int lf = f - (12288 + 36864 + 18432 + 8192), l = lf & 63, rest = lf >> 6;
    int kk = rest & 3, c16 = rest >> 2;
    sp = W2 + (size_t)(c16 * 16 + (l & 15)) * 128 + kk * 32 + (l >> 4) * 8;
    dp = w22 + (size_t)lf * 8;
  }
  float4 v0 = *(const float4*)sp;
  float4 v1 = *(const float4*)(sp + 4);
  *(bf16x8_t*)dp = pack8(v0, v1);
}

// ---------------------------------------------------------------------------
// Kernel 2: q projection. 256 blocks x 256 thr; 16 b-rows per block.
// q_ws[b][j] = sum_m q0[b,m]*Wq[j,m], effective K=256.
// ---------------------------------------------------------------------------
__global__ __launch_bounds__(256) void qproj_kernel(
    const float* __restrict__ src, const float* __restrict__ srct,
    const unsigned short* __restrict__ wq2, float* __restrict__ q_ws) {
  __shared__ unsigned short A[16][264];  // 132 dw pitch == 4 mod 32
  int b0 = blockIdx.x * 16;
  int t = threadIdx.x;
  for (int i = t; i < 512; i += 256) {   // 16 rows * 32 groups of 8
    int row = i >> 5, c8 = (i & 31) << 3;
    const float* sp = (c8 < 128) ? (src + (size_t)(b0 + row) * 128 + c8)
                                 : (srct + (size_t)(b0 + row) * 128 + (c8 - 128));
    float4 v0 = *(const float4*)sp;
    float4 v1 = *(const float4*)(sp + 4);
    *(bf16x8_t*)&A[row][c8] = pack8(v0, v1);
  }
  __syncthreads();
  int l = t & 63, w = t >> 6, lr = l & 15, lg = l >> 4;
  int col0 = w * 96;
  f32x4_t acc[6] = {};
#pragma unroll
  for (int ks = 0; ks < 8; ++ks) {
    bf16x8_t a = *(const bf16x8_t*)&A[lr][ks * 32 + lg * 8];
#pragma unroll
    for (int ct = 0; ct < 6; ++ct) {
      bf16x8_t bfr = *(const bf16x8_t*)(wq2 + (((size_t)(w * 6 + ct)) * 8 + ks) * 512 + l * 8);
      acc[ct] = __builtin_amdgcn_mfma_f32_16x16x32_bf16(a, bfr, acc[ct], 0, 0, 0);
    }
  }
#pragma unroll
  for (int ct = 0; ct < 6; ++ct) {
    int col = col0 + ct * 16 + lr;
#pragma unroll
    for (int r = 0; r < 4; ++r)
      q_ws[(size_t)(b0 + lg * 4 + r) * 384 + col] = acc[ct][r];
  }
}

// ---------------------------------------------------------------------------
// Kernel 3: mega. One block per b (4096 blocks, 512 thr = 8 waves, 2 blk/CU).
//  stage k0 (64x384 bf16, read ONCE) -> single MFMA pass: waves 0-3 compute
//  K cols 0..383, waves 4-7 compute V cols 0..383. Scores from K fragments
//  (per-lane dot + lr-butterfly -> sc[4][64]); softmax on 2 waves; PV from
//  V fragments (lg-butterfly). No KV LDS buffer. Static LDS = 53.25 KB.
// ---------------------------------------------------------------------------
__global__ __launch_bounds__(512, 4) void mega_kernel(
    const float* __restrict__ seq, const float* __restrict__ seq_e,
    const float* __restrict__ seq_t, const int* __restrict__ mask,
    const unsigned short* __restrict__ wkv2, const float* __restrict__ q_ws,
    float* __restrict__ attnout, float* __restrict__ attn_sq) {
  __shared__ unsigned short k0f[64][392];  // 196 dw pitch == 4 mod 32
  __shared__ float qv[384];
  __shared__ float sc[4][64];
  __shared__ float attn_l[2][64];

  int b = blockIdx.x;
  int t = threadIdx.x;
  int l = t & 63, w = t >> 6, lr = l & 15, lg = l >> 4;

  if (t < 384) qv[t] = q_ws[(size_t)b * 384 + t];

  // stage k0 = [seq | seq_e | seq_t] as bf16
  for (int i = t; i < 3072; i += 512) {  // 64 rows * 48 groups of 8
    int row = i / 48, c8 = (i - row * 48) << 3;
    const float* sp;
    if (c8 < 128)      sp = seq   + ((size_t)b * 64 + row) * 128 + c8;
    else if (c8 < 256) sp = seq_e + ((size_t)b * 64 + row) * 128 + (c8 - 128);
    else               sp = seq_t + ((size_t)b * 64 + row) * 128 + (c8 - 256);
    float4 v0 = *(const float4*)sp;
    float4 v1 = *(const float4*)(sp + 4);
    *(bf16x8_t*)&k0f[row][c8] = pack8(v0, v1);
  }
  __syncthreads();

  // GEMM: wave w<4 -> K cols w*96..+95; wave w>=4 -> V cols (w-4)*96..+95.
  int c16base = w * 6;  // wkv2 c16 index: K cols are c16 0..23, V cols 24..47
  f32x4_t acc[4][6] = {};
#pragma unroll
  for (int ks = 0; ks < 12; ++ks) {
    bf16x8_t a[4];
#pragma unroll
    for (int rt = 0; rt < 4; ++rt)
      a[rt] = *(const bf16x8_t*)&k0f[rt * 16 + lr][ks * 32 + lg * 8];
#pragma unroll
    for (int ct = 0; ct < 6; ++ct) {
      bf16x8_t bfr = *(const bf16x8_t*)(wkv2 + (((size_t)(c16base + ct)) * 12 + ks) * 512 + l * 8);
#pragma unroll
      for (int rt = 0; rt < 4; ++rt)
        acc[rt][ct] = __builtin_amdgcn_mfma_f32_16x16x32_bf16(a[rt], bfr, acc[rt][ct], 0, 0, 0);
    }
  }

  // Scores from K fragments (waves 0-3): lane holds K[row][col], col=w*96+ct*16+lr
  if (w < 4) {
    int col0 = w * 96;
    float qreg[6];
#pragma unroll
    for (int ct = 0; ct < 6; ++ct) qreg[ct] = qv[col0 + ct * 16 + lr];
    float part[4][4];
#pragma unroll
    for (int rt = 0; rt < 4; ++rt)
#pragma unroll
      for (int r = 0; r < 4; ++r) {
        float p = 0.f;
#pragma unroll
        for (int ct = 0; ct < 6; ++ct) p += acc[rt][ct][r] * qreg[ct];
        part[rt][r] = p;
      }
#pragma unroll
    for (int off = 1; off < 16; off <<= 1)
#pragma unroll
      for (int rt = 0; rt < 4; ++rt)
#pragma unroll
        for (int r = 0; r < 4; ++r)
          part[rt][r] += __shfl_xor(part[rt][r], off, 64);
    if (lr == 0) {
#pragma unroll
      for (int rt = 0; rt < 4; ++rt)
#pragma unroll
        for (int r = 0; r < 4; ++r)
          sc[w][rt * 16 + lg * 4 + r] = part[rt][r];
    }
  }
  __syncthreads();

  // Softmax: head0 = waves 0,1 partials; head1 = waves 2,3. t<128: h=w, n=l.
  if (t < 128) {
    int h = w, n = l;
    float s = (sc[h * 2 + 0][n] + sc[h * 2 + 1][n]) * 0.07216878364870323f;  // 1/sqrt(192)
    if (mask[b * 64 + n] != 0) s = -1e10f;
    float mx = s;
#pragma unroll
    for (int off = 32; off > 0; off >>= 1) mx = fmaxf(mx, __shfl_xor(mx, off, 64));
    float p = __expf(s - mx);
    float sm = p;
#pragma unroll
    for (int off = 32; off > 0; off >>= 1) sm += __shfl_xor(sm, off, 64);
    float a = p / sm;
    attn_l[h][n] = a;
    attn_sq[((size_t)h * 4096 + b) * 64 + n] = a;  // attn.transpose(1,0,2,3)
  }
  __syncthreads();

  // PV from V fragments (waves 4-7): lane holds V[row][vcol], vcol=(w-4)*96+ct*16+lr
  if (w >= 4) {
    int vcol0 = (w - 4) * 96;
    int h = (w >= 6);
    float areg[16];
#pragma unroll
    for (int rt = 0; rt < 4; ++rt)
#pragma unroll
      for (int r = 0; r < 4; ++r)
        areg[rt * 4 + r] = attn_l[h][rt * 16 + lg * 4 + r];
#pragma unroll
    for (int ct = 0; ct < 6; ++ct) {
      float p = 0.f;
#pragma unroll
      for (int rt = 0; rt < 4; ++rt)
#pragma unroll
        for (int r = 0; r < 4; ++r)
          p += areg[rt * 4 + r] * acc[rt][ct][r];
      p += __shfl_xor(p, 16, 64);
      p += __shfl_xor(p, 32, 64);
      if (lg == 0) attnout[(size_t)b * 384 + vcol0 + ct * 16 + lr] = p;
    }
  }
}

// ---------------------------------------------------------------------------
// Kernel 4: tail. 256 blocks x 256 thr; 16 b-rows each.
//  GEMM1 (Wo) -> +bo +q0 -> LN (lr-butterfly + LDS partials) -> X=[ln|src]
//  -> GEMM2 (W1)+relu -> GEMM3 (W2) -> y. Static LDS ~17.4 KB.
// ---------------------------------------------------------------------------
__global__ __launch_bounds__(256) void tail_kernel(
    const float* __restrict__ attnout, const float* __restrict__ src,
    const float* __restrict__ srct,
    const unsigned short* __restrict__ wo2, const unsigned short* __restrict__ w12,
    const unsigned short* __restrict__ w22,
    const float* __restrict__ bo, const float* __restrict__ lng,
    const float* __restrict__ lnb, const float* __restrict__ b1,
    const float* __restrict__ b2, float* __restrict__ y) {
  __shared__ unsigned short R[16][392];   // A1 (attnout bf16), then Xa (ln out)
  __shared__ unsigned short Xs[16][136];  // src bf16, then Hl (relu hidden)
  __shared__ float psum[16][4], psq[16][4];

  int b0 = blockIdx.x * 16;
  int t = threadIdx.x;
  int l = t & 63, w = t >> 6, lr = l & 15, lg = l >> 4;

  for (int i = t; i < 768; i += 256) {  // 16 rows * 48 groups
    int row = i / 48, c8 = (i - row * 48) << 3;
    const float* sp = attnout + (size_t)(b0 + row) * 384 + c8;
    float4 v0 = *(const float4*)sp;
    float4 v1 = *(const float4*)(sp + 4);
    *(bf16x8_t*)&R[row][c8] = pack8(v0, v1);
  }
  {
    int i = t; int row = i >> 4, c8 = (i & 15) << 3;  // 16 rows * 16 groups = 256
    const float* sp = src + (size_t)(b0 + row) * 128 + c8;
    float4 v0 = *(const float4*)sp;
    float4 v1 = *(const float4*)(sp + 4);
    *(bf16x8_t*)&Xs[row][c8] = pack8(v0, v1);
  }
  __syncthreads();

  // GEMM1: out1 = attnout @ Wo^T   (16 x 384 x 384)
  int col0 = w * 96;
  f32x4_t acc[6] = {};
#pragma unroll
  for (int ks = 0; ks < 12; ++ks) {
    bf16x8_t a = *(const bf16x8_t*)&R[lr][ks * 32 + lg * 8];
#pragma unroll
    for (int ct = 0; ct < 6; ++ct) {
      bf16x8_t bfr = *(const bf16x8_t*)(wo2 + (((size_t)(w * 6 + ct)) * 12 + ks) * 512 + l * 8);
      acc[ct] = __builtin_amdgcn_mfma_f32_16x16x32_bf16(a, bfr, acc[ct], 0, 0, 0);
    }
  }

  // residual + per-row sum/sumsq partials
  float bov[6];
#pragma unroll
  for (int ct = 0; ct < 6; ++ct) bov[ct] = bo[col0 + ct * 16 + lr];
#pragma unroll
  for (int r = 0; r < 4; ++r) {
    int row = lg * 4 + r;
    float s = 0.f, ss = 0.f;
#pragma unroll
    for (int ct = 0; ct < 6; ++ct) {
      int col = col0 + ct * 16 + lr;
      float v = acc[ct][r] + bov[ct];
      if (col < 128) v += src[(size_t)(b0 + row) * 128 + col];
      else if (col >= 256) v += srct[(size_t)(b0 + row) * 128 + (col - 256)];
      acc[ct][r] = v;
      s += v; ss += v * v;
    }
#pragma unroll
    for (int off = 1; off < 16; off <<= 1) {
      s += __shfl_xor(s, off, 64);
      ss += __shfl_xor(ss, off, 64);
    }
    if (lr == 0) { psum[row][w] = s; psq[row][w] = ss; }
  }
  __syncthreads();  // partials ready; all GEMM1 reads of R done

  // LN -> write Xa into R
  float gcv[6], bcv[6];
#pragma unroll
  for (int ct = 0; ct < 6; ++ct) {
    gcv[ct] = lng[col0 + ct * 16 + lr];
    bcv[ct] = lnb[col0 + ct * 16 + lr];
  }
#pragma unroll
  for (int r = 0; r < 4; ++r) {
    int row = lg * 4 + r;
    float s4 = psum[row][0] + psum[row][1] + psum[row][2] + psum[row][3];
    float q4 = psq[row][0] + psq[row][1] + psq[row][2] + psq[row][3];
    float m = s4 * (1.f / 384.f);
    float var = q4 * (1.f / 384.f) - m * m;
    float rs = rsqrtf(var + 1e-5f);
#pragma unroll
    for (int ct = 0; ct < 6; ++ct) {
      int col = col0 + ct * 16 + lr;
      R[row][col] = f2bf((acc[ct][r] - m) * rs * gcv[ct] + bcv[ct]);
    }
  }
  __syncthreads();

  // GEMM2: h = relu(X @ W1^T + b1)  (16 x 128 x 512); X = [Xa(384) | Xs(128)]
  int c20 = w * 32;
  f32x4_t acc2[2] = {};
#pragma unroll
  for (int ks = 0; ks < 16; ++ks) {
    bf16x8_t a = (ks < 12) ? *(const bf16x8_t*)&R[lr][ks * 32 + lg * 8]
                           : *(const bf16x8_t*)&Xs[lr][(ks - 12) * 32 + lg * 8];
#pragma unroll
    for (int ct = 0; ct < 2; ++ct) {
      bf16x8_t bfr = *(const bf16x8_t*)(w12 + (((size_t)(w * 2 + ct)) * 16 + ks) * 512 + l * 8);
      acc2[ct] = __builtin_amdgcn_mfma_f32_16x16x32_bf16(a, bfr, acc2[ct], 0, 0, 0);
    }
  }
  __syncthreads();  // all GEMM2 reads of Xs done before Hl overlay
#pragma unroll
  for (int ct = 0; ct < 2; ++ct) {
    int col = c20 + ct * 16 + lr;
    float bb = b1[col];
#pragma unroll
    for (int r = 0; r < 4; ++r)
      Xs[lg * 4 + r][col] = f2bf(fmaxf(acc2[ct][r] + bb, 0.f));
  }
  __syncthreads();

  // GEMM3: y = H @ W2^T + b2  (16 x 128 x 128)
  f32x4_t acc3[2] = {};
#pragma unroll
  for (int ks = 0; ks < 4; ++ks) {
    bf16x8_t a = *(const bf16x8_t*)&Xs[lr][ks * 32 + lg * 8];
#pragma unroll
    for (int ct = 0; ct < 2; ++ct) {
      bf16x8_t bfr = *(const bf16x8_t*)(w22 + (((size_t)(w * 2 + ct)) * 4 + ks) * 512 + l * 8);
      acc3[ct] = __builtin_amdgcn_mfma_f32_16x16x32_bf16(a, bfr, acc3[ct], 0, 0, 0);
    }
  }
#pragma unroll
  for (int ct = 0; ct < 2; ++ct) {
    int col = c20 + ct * 16 + lr;
    float bb = b2[col];
#pragma unroll
    for (int r = 0; r < 4; ++r)
      y[(size_t)(b0 + lg * 4 + r) * 128 + col] = acc3[ct][r] + bb;
  }
}

// ---------------------------------------------------------------------------
extern "C" void kernel_launch(void* const* d_in, const int* in_sizes, int n_in,
                              void* d_out, int out_size, void* d_ws, size_t ws_size,
                              hipStream_t stream) {
  const float* src   = (const float*)d_in[0];
  const float* src_t = (const float*)d_in[1];
  const float* seq   = (const float*)d_in[2];
  const float* seq_t = (const float*)d_in[3];
  const float* seq_e = (const float*)d_in[4];
  const int*   mask  = (const int*)d_in[5];
  const float* Wq = (const float*)d_in[6];
  const float* Wk = (const float*)d_in[7];
  const float* Wv = (const float*)d_in[8];
  const float* Wo = (const float*)d_in[9];
  const float* bo = (const float*)d_in[10];
  const float* ln_g = (const float*)d_in[11];
  const float* ln_b = (const float*)d_in[12];
  const float* W1 = (const float*)d_in[13];
  const float* b1 = (const float*)d_in[14];
  const float* W2 = (const float*)d_in[15];
  const float* b2 = (const float*)d_in[16];

  float* y_out    = (float*)d_out;        // [4096][128]
  float* attn_out = y_out + 4096 * 128;   // [8192][64]

  char* ws = (char*)d_ws;
  unsigned short* wq2  = (unsigned short*)ws;  ws += 98304 * 2;
  unsigned short* wkv2 = (unsigned short*)ws;  ws += 294912 * 2;
  unsigned short* wo2  = (unsigned short*)ws;  ws += 147456 * 2;
  unsigned short* w12  = (unsigned short*)ws;  ws += 65536 * 2;
  unsigned short* w22  = (unsigned short*)ws;  ws += 16384 * 2;
  float* q_ws    = (float*)ws;                 ws += (size_t)4096 * 384 * 4;
  float* attnout = (float*)ws;                 ws += (size_t)4096 * 384 * 4;

  prep_kernel<<<dim3(304), dim3(256), 0, stream>>>(Wq, Wk, Wv, Wo, W1, W2,
                                                   wq2, wkv2, wo2, w12, w22);
  qproj_kernel<<<dim3(256), dim3(256), 0, stream>>>(src, src_t, wq2, q_ws);
  mega_kernel<<<dim3(4096), dim3(512), 0, stream>>>(seq, seq_e, seq_t, mask,
                                                    wkv2, q_ws, attnout, attn_out);
  tail_kernel<<<dim3(256), dim3(256), 0, stream>>>(attnout, src, src_t,
                                                   wo2, w12, w22,
                                                   bo, ln_g, ln_b, b1, b2, y_out);
}

// Round 3
// 586.190 us; speedup vs baseline: 2.0152x; 2.0152x over previous
//
#include <hip/hip_runtime.h>
#include <hip/hip_bf16.h>

// TGAT fused forward on MI355X (gfx950).
// Shapes: B=4096, N=64, D=De=Dt=128, M=384, H=2, DK=192.
// R2: mega split into two register passes (K then V) so per-wave acc = 48
// regs; total regs ~100 <= 128 budget at 4 waves/SIMD (R1 spilled: 96-reg
// acc + operands > 128 -> 2.3 GB scratch writes). Weights fragment-major.

typedef __attribute__((ext_vector_type(8))) short bf16x8_t;   // 8 bf16 in 4 VGPRs
typedef __attribute__((ext_vector_type(4))) float f32x4_t;    // MFMA accumulator

__device__ __forceinline__ float bf2f(unsigned short s) {
  union { unsigned u; float f; } v; v.u = ((unsigned)s) << 16; return v.f;
}
__device__ __forceinline__ unsigned short f2bf(float f) {
  union { float f; unsigned u; } v; v.f = f;
  return (unsigned short)((v.u + 0x7fffu + ((v.u >> 16) & 1u)) >> 16);  // RNE
}
__device__ __forceinline__ bf16x8_t pack8(float4 a, float4 b) {
  bf16x8_t t;
  t[0] = (short)f2bf(a.x); t[1] = (short)f2bf(a.y);
  t[2] = (short)f2bf(a.z); t[3] = (short)f2bf(a.w);
  t[4] = (short)f2bf(b.x); t[5] = (short)f2bf(b.y);
  t[6] = (short)f2bf(b.z); t[7] = (short)f2bf(b.w);
  return t;
}

// ---------------------------------------------------------------------------
// Kernel 1: repack all weights to bf16 FRAGMENT-MAJOR layouts.
// For W[C][K]: packed[(c16*(K/32)+kk)*512 + l*8 + j] = W[c16*16+(l&15)][kk*32+(l>>4)*8+j]
// so a wave's MFMA B-fragment load is one contiguous 1KB burst.
// ---------------------------------------------------------------------------
__global__ __launch_bounds__(256) void prep_kernel(
    const float* __restrict__ Wq, const float* __restrict__ Wk,
    const float* __restrict__ Wv, const float* __restrict__ Wo,
    const float* __restrict__ W1, const float* __restrict__ W2,
    unsigned short* __restrict__ wq2, unsigned short* __restrict__ wkv2,
    unsigned short* __restrict__ wo2, unsigned short* __restrict__ w12,
    unsigned short* __restrict__ w22) {
  int f = blockIdx.x * 256 + threadIdx.x;
  if (f >= 77824) return;
  const float* sp;
  unsigned short* dp;
  if (f < 12288) {                    // wq2: C=384, Keff=256 (skip Wq cols 128..255)
    int lf = f, l = lf & 63, rest = lf >> 6;
    int kk = rest & 7, c16 = rest >> 3;
    int r = c16 * 16 + (l & 15), k0 = kk * 32 + (l >> 4) * 8;
    int m0 = (k0 < 128) ? k0 : k0 + 128;
    sp = Wq + (size_t)r * 384 + m0;
    dp = wq2 + (size_t)lf * 8;
  } else if (f < 12288 + 36864) {     // wkv2: C=768 (Wk rows then Wv rows), K=384
    int lf = f - 12288, l = lf & 63, rest = lf >> 6;
    int kk = rest % 12, c16 = rest / 12;
    int j = c16 * 16 + (l & 15), m0 = kk * 32 + (l >> 4) * 8;
    sp = (j < 384 ? Wk + (size_t)j * 384 : Wv + (size_t)(j - 384) * 384) + m0;
    dp = wkv2 + (size_t)lf * 8;
  } else if (f < 12288 + 36864 + 18432) {  // wo2: C=384, K=384
    int lf = f - (12288 + 36864), l = lf & 63, rest = lf >> 6;
    int kk = rest % 12, c16 = rest / 12;
    sp = Wo + (size_t)(c16 * 16 + (l & 15)) * 384 + kk * 32 + (l >> 4) * 8;
    dp = wo2 + (size_t)lf * 8;
  } else if (f < 12288 + 36864 + 18432 + 8192) {  // w12: C=128, K=512
    int lf = f - (12288 + 36864 + 18432), l = lf & 63, rest = lf >> 6;
    int kk = rest & 15, c16 = rest >> 4;
    sp = W1 + (size_t)(c16 * 16 + (l & 15)) * 512 + kk * 32 + (l >> 4) * 8;
    dp = w12 + (size_t)lf * 8;
  } else {                            // w22: C=128, K=128
    int lf = f - (12288 + 36864 + 18432 + 8192), l = lf & 63, rest = lf >> 6;
    int kk = rest & 3, c16 = rest >> 2;
    sp = W2 + (size_t)(c16 * 16 + (l & 15)) * 128 + kk * 32 + (l >> 4) * 8;
    dp = w22 + (size_t)lf * 8;
  }
  float4 v0 = *(const float4*)sp;
  float4 v1 = *(const float4*)(sp + 4);
  *(bf16x8_t*)dp = pack8(v0, v1);
}

// ---------------------------------------------------------------------------
// Kernel 2: q projection. 256 blocks x 256 thr; 16 b-rows per block.
// ---------------------------------------------------------------------------
__global__ __launch_bounds__(256) void qproj_kernel(
    const float* __restrict__ src, const float* __restrict__ srct,
    const unsigned short* __restrict__ wq2, float* __restrict__ q_ws) {
  __shared__ unsigned short A[16][264];
  int b0 = blockIdx.x * 16;
  int t = threadIdx.x;
  for (int i = t; i < 512; i += 256) {
    int row = i >> 5, c8 = (i & 31) << 3;
    const float* sp = (c8 < 128) ? (src + (size_t)(b0 + row) * 128 + c8)
                                 : (srct + (size_t)(b0 + row) * 128 + (c8 - 128));
    float4 v0 = *(const float4*)sp;
    float4 v1 = *(const float4*)(sp + 4);
    *(bf16x8_t*)&A[row][c8] = pack8(v0, v1);
  }
  __syncthreads();
  int l = t & 63, w = t >> 6, lr = l & 15, lg = l >> 4;
  int col0 = w * 96;
  f32x4_t acc[6] = {};
#pragma unroll
  for (int ks = 0; ks < 8; ++ks) {
    bf16x8_t a = *(const bf16x8_t*)&A[lr][ks * 32 + lg * 8];
#pragma unroll
    for (int ct = 0; ct < 6; ++ct) {
      bf16x8_t bfr = *(const bf16x8_t*)(wq2 + (((size_t)(w * 6 + ct)) * 8 + ks) * 512 + l * 8);
      acc[ct] = __builtin_amdgcn_mfma_f32_16x16x32_bf16(a, bfr, acc[ct], 0, 0, 0);
    }
  }
#pragma unroll
  for (int ct = 0; ct < 6; ++ct) {
    int col = col0 + ct * 16 + lr;
#pragma unroll
    for (int r = 0; r < 4; ++r)
      q_ws[(size_t)(b0 + lg * 4 + r) * 384 + col] = acc[ct][r];
  }
}

// ---------------------------------------------------------------------------
// Kernel 3: mega. One block per b (4096 blocks, 512 thr = 8 waves).
//  Pass 1: K = k0 @ Wk^T, all 8 waves x 48 cols (acc[4][3] = 48 regs);
//          scores via per-lane dot + lr-butterfly -> sc[8][64].
//  softmax (t<128) -> attn_l, attn_sq.
//  Pass 2: V = k0 @ Wv^T (reuses acc regs); PV via lg-butterfly -> attnout.
//  Static LDS = 54272 B; ~100 regs -> 2 blocks/CU, no spill.
// ---------------------------------------------------------------------------
__global__ __launch_bounds__(512, 4) void mega_kernel(
    const float* __restrict__ seq, const float* __restrict__ seq_e,
    const float* __restrict__ seq_t, const int* __restrict__ mask,
    const unsigned short* __restrict__ wkv2, const float* __restrict__ q_ws,
    float* __restrict__ attnout, float* __restrict__ attn_sq) {
  __shared__ unsigned short k0f[64][392];  // 196 dw pitch == 4 mod 32
  __shared__ float qv[384];
  __shared__ float sc[8][64];
  __shared__ float attn_l[2][64];

  int b = blockIdx.x;
  int t = threadIdx.x;
  int l = t & 63, w = t >> 6, lr = l & 15, lg = l >> 4;

  if (t < 384) qv[t] = q_ws[(size_t)b * 384 + t];

  // stage k0 = [seq | seq_e | seq_t] as bf16 (read once)
  for (int i = t; i < 3072; i += 512) {  // 64 rows * 48 groups of 8
    int row = i / 48, c8 = (i - row * 48) << 3;
    const float* sp;
    if (c8 < 128)      sp = seq   + ((size_t)b * 64 + row) * 128 + c8;
    else if (c8 < 256) sp = seq_e + ((size_t)b * 64 + row) * 128 + (c8 - 128);
    else               sp = seq_t + ((size_t)b * 64 + row) * 128 + (c8 - 256);
    float4 v0 = *(const float4*)sp;
    float4 v1 = *(const float4*)(sp + 4);
    *(bf16x8_t*)&k0f[row][c8] = pack8(v0, v1);
  }
  __syncthreads();

  // ---- Pass 1: K-GEMM. wave w -> K cols w*48 .. w*48+47 (c16 = w*3+ct) ----
  {
    f32x4_t acc[4][3] = {};
#pragma unroll 2
    for (int ks = 0; ks < 12; ++ks) {
      bf16x8_t a[4];
#pragma unroll
      for (int rt = 0; rt < 4; ++rt)
        a[rt] = *(const bf16x8_t*)&k0f[rt * 16 + lr][ks * 32 + lg * 8];
#pragma unroll
      for (int ct = 0; ct < 3; ++ct) {
        bf16x8_t bfr = *(const bf16x8_t*)(wkv2 + (((size_t)(w * 3 + ct)) * 12 + ks) * 512 + l * 8);
#pragma unroll
        for (int rt = 0; rt < 4; ++rt)
          acc[rt][ct] = __builtin_amdgcn_mfma_f32_16x16x32_bf16(a[rt], bfr, acc[rt][ct], 0, 0, 0);
      }
    }
    // scores: lane holds K[row][col], col = w*48 + ct*16 + lr
    float qreg[3];
#pragma unroll
    for (int ct = 0; ct < 3; ++ct) qreg[ct] = qv[w * 48 + ct * 16 + lr];
    float part[4][4];
#pragma unroll
    for (int rt = 0; rt < 4; ++rt)
#pragma unroll
      for (int r = 0; r < 4; ++r) {
        float p = 0.f;
#pragma unroll
        for (int ct = 0; ct < 3; ++ct) p += acc[rt][ct][r] * qreg[ct];
        part[rt][r] = p;
      }
#pragma unroll
    for (int off = 1; off < 16; off <<= 1)
#pragma unroll
      for (int rt = 0; rt < 4; ++rt)
#pragma unroll
        for (int r = 0; r < 4; ++r)
          part[rt][r] += __shfl_xor(part[rt][r], off, 64);
    if (lr == 0) {
#pragma unroll
      for (int rt = 0; rt < 4; ++rt)
#pragma unroll
        for (int r = 0; r < 4; ++r)
          sc[w][rt * 16 + lg * 4 + r] = part[rt][r];
    }
  }
  __syncthreads();

  // softmax on waves 0-1 (h = w, n = l); head h sums waves 4h..4h+3
  if (t < 128) {
    int h = w, n = l;
    float s = (sc[h * 4 + 0][n] + sc[h * 4 + 1][n] + sc[h * 4 + 2][n] + sc[h * 4 + 3][n])
              * 0.07216878364870323f;  // 1/sqrt(192)
    if (mask[b * 64 + n] != 0) s = -1e10f;
    float mx = s;
#pragma unroll
    for (int off = 32; off > 0; off >>= 1) mx = fmaxf(mx, __shfl_xor(mx, off, 64));
    float p = __expf(s - mx);
    float sm = p;
#pragma unroll
    for (int off = 32; off > 0; off >>= 1) sm += __shfl_xor(sm, off, 64);
    float a = p / sm;
    attn_l[h][n] = a;
    attn_sq[((size_t)h * 4096 + b) * 64 + n] = a;  // attn.transpose(1,0,2,3)
  }

  // ---- Pass 2: V-GEMM (no dependence on softmax; overlaps it) ----
  {
    f32x4_t acc[4][3] = {};
#pragma unroll 2
    for (int ks = 0; ks < 12; ++ks) {
      bf16x8_t a[4];
#pragma unroll
      for (int rt = 0; rt < 4; ++rt)
        a[rt] = *(const bf16x8_t*)&k0f[rt * 16 + lr][ks * 32 + lg * 8];
#pragma unroll
      for (int ct = 0; ct < 3; ++ct) {
        bf16x8_t bfr = *(const bf16x8_t*)(wkv2 + (((size_t)(24 + w * 3 + ct)) * 12 + ks) * 512 + l * 8);
#pragma unroll
        for (int rt = 0; rt < 4; ++rt)
          acc[rt][ct] = __builtin_amdgcn_mfma_f32_16x16x32_bf16(a[rt], bfr, acc[rt][ct], 0, 0, 0);
      }
    }
    __syncthreads();  // attn_l ready
    // PV: lane holds V[row][vcol], vcol = w*48 + ct*16 + lr; head = (w >= 4)
    int h = (w >= 4);
    float areg[16];
#pragma unroll
    for (int rt = 0; rt < 4; ++rt)
#pragma unroll
      for (int r = 0; r < 4; ++r)
        areg[rt * 4 + r] = attn_l[h][rt * 16 + lg * 4 + r];
#pragma unroll
    for (int ct = 0; ct < 3; ++ct) {
      float p = 0.f;
#pragma unroll
      for (int rt = 0; rt < 4; ++rt)
#pragma unroll
        for (int r = 0; r < 4; ++r)
          p += areg[rt * 4 + r] * acc[rt][ct][r];
      p += __shfl_xor(p, 16, 64);
      p += __shfl_xor(p, 32, 64);
      if (lg == 0) attnout[(size_t)b * 384 + w * 48 + ct * 16 + lr] = p;
    }
  }
}

// ---------------------------------------------------------------------------
// Kernel 4: tail. 256 blocks x 256 thr; 16 b-rows each.
// ---------------------------------------------------------------------------
__global__ __launch_bounds__(256) void tail_kernel(
    const float* __restrict__ attnout, const float* __restrict__ src,
    const float* __restrict__ srct,
    const unsigned short* __restrict__ wo2, const unsigned short* __restrict__ w12,
    const unsigned short* __restrict__ w22,
    const float* __restrict__ bo, const float* __restrict__ lng,
    const float* __restrict__ lnb, const float* __restrict__ b1,
    const float* __restrict__ b2, float* __restrict__ y) {
  __shared__ unsigned short R[16][392];   // A1 (attnout bf16), then Xa (ln out)
  __shared__ unsigned short Xs[16][136];  // src bf16, then Hl (relu hidden)
  __shared__ float psum[16][4], psq[16][4];

  int b0 = blockIdx.x * 16;
  int t = threadIdx.x;
  int l = t & 63, w = t >> 6, lr = l & 15, lg = l >> 4;

  for (int i = t; i < 768; i += 256) {
    int row = i / 48, c8 = (i - row * 48) << 3;
    const float* sp = attnout + (size_t)(b0 + row) * 384 + c8;
    float4 v0 = *(const float4*)sp;
    float4 v1 = *(const float4*)(sp + 4);
    *(bf16x8_t*)&R[row][c8] = pack8(v0, v1);
  }
  {
    int i = t; int row = i >> 4, c8 = (i & 15) << 3;
    const float* sp = src + (size_t)(b0 + row) * 128 + c8;
    float4 v0 = *(const float4*)sp;
    float4 v1 = *(const float4*)(sp + 4);
    *(bf16x8_t*)&Xs[row][c8] = pack8(v0, v1);
  }
  __syncthreads();

  // GEMM1: out1 = attnout @ Wo^T   (16 x 384 x 384)
  int col0 = w * 96;
  f32x4_t acc[6] = {};
#pragma unroll
  for (int ks = 0; ks < 12; ++ks) {
    bf16x8_t a = *(const bf16x8_t*)&R[lr][ks * 32 + lg * 8];
#pragma unroll
    for (int ct = 0; ct < 6; ++ct) {
      bf16x8_t bfr = *(const bf16x8_t*)(wo2 + (((size_t)(w * 6 + ct)) * 12 + ks) * 512 + l * 8);
      acc[ct] = __builtin_amdgcn_mfma_f32_16x16x32_bf16(a, bfr, acc[ct], 0, 0, 0);
    }
  }

  float bov[6];
#pragma unroll
  for (int ct = 0; ct < 6; ++ct) bov[ct] = bo[col0 + ct * 16 + lr];
#pragma unroll
  for (int r = 0; r < 4; ++r) {
    int row = lg * 4 + r;
    float s = 0.f, ss = 0.f;
#pragma unroll
    for (int ct = 0; ct < 6; ++ct) {
      int col = col0 + ct * 16 + lr;
      float v = acc[ct][r] + bov[ct];
      if (col < 128) v += src[(size_t)(b0 + row) * 128 + col];
      else if (col >= 256) v += srct[(size_t)(b0 + row) * 128 + (col - 256)];
      acc[ct][r] = v;
      s += v; ss += v * v;
    }
#pragma unroll
    for (int off = 1; off < 16; off <<= 1) {
      s += __shfl_xor(s, off, 64);
      ss += __shfl_xor(ss, off, 64);
    }
    if (lr == 0) { psum[row][w] = s; psq[row][w] = ss; }
  }
  __syncthreads();

  float gcv[6], bcv[6];
#pragma unroll
  for (int ct = 0; ct < 6; ++ct) {
    gcv[ct] = lng[col0 + ct * 16 + lr];
    bcv[ct] = lnb[col0 + ct * 16 + lr];
  }
#pragma unroll
  for (int r = 0; r < 4; ++r) {
    int row = lg * 4 + r;
    float s4 = psum[row][0] + psum[row][1] + psum[row][2] + psum[row][3];
    float q4 = psq[row][0] + psq[row][1] + psq[row][2] + psq[row][3];
    float m = s4 * (1.f / 384.f);
    float var = q4 * (1.f / 384.f) - m * m;
    float rs = rsqrtf(var + 1e-5f);
#pragma unroll
    for (int ct = 0; ct < 6; ++ct) {
      int col = col0 + ct * 16 + lr;
      R[row][col] = f2bf((acc[ct][r] - m) * rs * gcv[ct] + bcv[ct]);
    }
  }
  __syncthreads();

  // GEMM2: h = relu(X @ W1^T + b1)  (16 x 128 x 512); X = [Xa(384) | Xs(128)]
  int c20 = w * 32;
  f32x4_t acc2[2] = {};
#pragma unroll
  for (int ks = 0; ks < 16; ++ks) {
    bf16x8_t a = (ks < 12) ? *(const bf16x8_t*)&R[lr][ks * 32 + lg * 8]
                           : *(const bf16x8_t*)&Xs[lr][(ks - 12) * 32 + lg * 8];
#pragma unroll
    for (int ct = 0; ct < 2; ++ct) {
      bf16x8_t bfr = *(const bf16x8_t*)(w12 + (((size_t)(w * 2 + ct)) * 16 + ks) * 512 + l * 8);
      acc2[ct] = __builtin_amdgcn_mfma_f32_16x16x32_bf16(a, bfr, acc2[ct], 0, 0, 0);
    }
  }
  __syncthreads();
#pragma unroll
  for (int ct = 0; ct < 2; ++ct) {
    int col = c20 + ct * 16 + lr;
    float bb = b1[col];
#pragma unroll
    for (int r = 0; r < 4; ++r)
      Xs[lg * 4 + r][col] = f2bf(fmaxf(acc2[ct][r] + bb, 0.f));
  }
  __syncthreads();

  // GEMM3: y = H @ W2^T + b2  (16 x 128 x 128)
  f32x4_t acc3[2] = {};
#pragma unroll
  for (int ks = 0; ks < 4; ++ks) {
    bf16x8_t a = *(const bf16x8_t*)&Xs[lr][ks * 32 + lg * 8];
#pragma unroll
    for (int ct = 0; ct < 2; ++ct) {
      bf16x8_t bfr = *(const bf16x8_t*)(w22 + (((size_t)(w * 2 + ct)) * 4 + ks) * 512 + l * 8);
      acc3[ct] = __builtin_amdgcn_mfma_f32_16x16x32_bf16(a, bfr, acc3[ct], 0, 0, 0);
    }
  }
#pragma unroll
  for (int ct = 0; ct < 2; ++ct) {
    int col = c20 + ct * 16 + lr;
    float bb = b2[col];
#pragma unroll
    for (int r = 0; r < 4; ++r)
      y[(size_t)(b0 + lg * 4 + r) * 128 + col] = acc3[ct][r] + bb;
  }
}

// ---------------------------------------------------------------------------
extern "C" void kernel_launch(void* const* d_in, const int* in_sizes, int n_in,
                              void* d_out, int out_size, void* d_ws, size_t ws_size,
                              hipStream_t stream) {
  const float* src   = (const float*)d_in[0];
  const float* src_t = (const float*)d_in[1];
  const float* seq   = (const float*)d_in[2];
  const float* seq_t = (const float*)d_in[3];
  const float* seq_e = (const float*)d_in[4];
  const int*   mask  = (const int*)d_in[5];
  const float* Wq = (const float*)d_in[6];
  const float* Wk = (const float*)d_in[7];
  const float* Wv = (const float*)d_in[8];
  const float* Wo = (const float*)d_in[9];
  const float* bo = (const float*)d_in[10];
  const float* ln_g = (const float*)d_in[11];
  const float* ln_b = (const float*)d_in[12];
  const float* W1 = (const float*)d_in[13];
  const float* b1 = (const float*)d_in[14];
  const float* W2 = (const float*)d_in[15];
  const float* b2 = (const float*)d_in[16];

  float* y_out    = (float*)d_out;        // [4096][128]
  float* attn_out = y_out + 4096 * 128;   // [8192][64]

  char* ws = (char*)d_ws;
  unsigned short* wq2  = (unsigned short*)ws;  ws += 98304 * 2;
  unsigned short* wkv2 = (unsigned short*)ws;  ws += 294912 * 2;
  unsigned short* wo2  = (unsigned short*)ws;  ws += 147456 * 2;
  unsigned short* w12  = (unsigned short*)ws;  ws += 65536 * 2;
  unsigned short* w22  = (unsigned short*)ws;  ws += 16384 * 2;
  float* q_ws    = (float*)ws;                 ws += (size_t)4096 * 384 * 4;
  float* attnout = (float*)ws;                 ws += (size_t)4096 * 384 * 4;

  prep_kernel<<<dim3(304), dim3(256), 0, stream>>>(Wq, Wk, Wv, Wo, W1, W2,
                                                   wq2, wkv2, wo2, w12, w22);
  qproj_kernel<<<dim3(256), dim3(256), 0, stream>>>(src, src_t, wq2, q_ws);
  mega_kernel<<<dim3(4096), dim3(512), 0, stream>>>(seq, seq_e, seq_t, mask,
                                                    wkv2, q_ws, attnout, attn_out);
  tail_kernel<<<dim3(256), dim3(256), 0, stream>>>(attnout, src, src_t,
                                                   wo2, w12, w22,
                                                   bo, ln_g, ln_b, b1, b2, y_out);
}